// Round 13
// baseline (581.222 us; speedup 1.0000x reference)
//
#include <hip/hip_runtime.h>
#include <stdint.h>

// HashEmbedder (Instant-NGP multires hash grid), 16 levels, F=2, T=2^19,
// N = 2^21 points.
//
// Round-13 = round-12 with coarse+mid+untile FUSED into final_kernel:
// voxel-cluster tables V0-V6 for ALL dense levels 0-6 (2 dwordx4 = 1 line
// per pt per level), issued 14-wide in a single BB, plus coalesced reads
// of the 9 fine slices, writing [N,32] f32 directly. Removes two
// serialized passes and the lvl_out round-trip for levels 0-6.
// fine_kernel (levels 7-15) unchanged: 341us = request-rate ceiling
// (~0.55 req/cyc/CU, confirmed across r6/r9/r10/r11 variants).
//
//   pass 0 : pack f32 tables -> bf16x2 (levels 7-15 only).
//   pass 0b: dense grids D0-6 (D0-2 = dense012 layout); voxel clusters
//            V0-V6 assembled from D (cache-local reads).
//   pass C : levels 7-15 hashed, level-at-a-time, paired -> slices 7-15.
//   final  : levels 0-6 via V-tables + read slices 7-15 -> out [N,32].

constexpr int kLevels = 16;
constexpr int kPoints = 1 << 21;
constexpr uint32_t kTableSize = 1u << 19;
constexpr uint32_t kMask = kTableSize - 1u;
constexpr size_t kPackedBytes = (size_t)kLevels * kTableSize * 4;  // 32 MB
constexpr size_t kLvlOutBytes = (size_t)kLevels * kPoints * 4;     // 128 MB

typedef float f32x4 __attribute__((ext_vector_type(4)));
typedef uint32_t u32x4 __attribute__((ext_vector_type(4)));

// dense grids (levels 0-2 packed together = dense012)
constexpr int kS0 = 17, kS1 = 21, kS2 = 26;            // res+1
constexpr int kN0 = kS0 * kS0 * kS0;                   // 4913
constexpr int kN1 = kS1 * kS1 * kS1;                   // 9261
constexpr int kN2 = kS2 * kS2 * kS2;                   // 17576
constexpr int kB1 = kN0, kB2 = kN0 + kN1;
constexpr int kNDense = kN0 + kN1 + kN2;               // 31750

// voxel-cluster tables V0-V6: S^3 slots x 32B
constexpr int kV0n = 17 * 17 * 17;   // 4913
constexpr int kV1n = 21 * 21 * 21;   // 9261
constexpr int kV2n = 26 * 26 * 26;   // 17576
constexpr int kV3n = 33 * 33 * 33;   // 35937
constexpr int kV4n = 41 * 41 * 41;   // 68921
constexpr int kV5n = 51 * 51 * 51;   // 132651
constexpr int kV6n = 65 * 65 * 65;   // 274625
constexpr int kVAll = kV0n + kV1n + kV2n + kV3n + kV4n + kV5n + kV6n; // 543884

// ws layout (freed packed[0..6] region = 14 MB):
constexpr size_t kV0Base = 131072;                          // after dense012
constexpr size_t kV1Base = kV0Base + (size_t)kV0n * 32;     // 288288
constexpr size_t kV2Base = kV1Base + (size_t)kV1n * 32;     // 584640
constexpr size_t kV3Base = kV2Base + (size_t)kV2n * 32;     // 1147072
constexpr size_t kV4Base = kV3Base + (size_t)kV3n * 32;     // 2297056
constexpr size_t kV5Base = kV4Base + (size_t)kV4n * 32;     // 4502528
// V5 end = 8747360.  D3-6 (S^3 x 4B) after V5:
constexpr size_t kD3Base = 8748032;
constexpr size_t kD4Base = 8892160;   // D3 end 8891780
constexpr size_t kD5Base = 9168128;   // D4 end 9167844
constexpr size_t kD6Base = 9699072;   // D5 end 9698732
// D6 end = 10797572 < 14680064 (freed region). OK.
// V6 (8.8MB) -> lvl_out slices 0-1 (levels 0-6 never materialized now):
constexpr size_t kV6Base = kPackedBytes;

// floor(16 * b^i), b = exp(ln(32)/15) in f64 (boundary levels round up).
__constant__ float c_res[kLevels] = {
    16.f, 20.f, 25.f, 32.f, 40.f, 50.f, 64.f, 80.f,
    101.f, 128.f, 161.f, 203.f, 256.f, 322.f, 406.f, 512.f};

__device__ __forceinline__ uint32_t bf16_rtne_hi(float f) {
    uint32_t u = __float_as_uint(f);
    return (u + 0x7FFFu + ((u >> 16) & 1u)) >> 16;
}
__device__ __forceinline__ float bflo(uint32_t e) {
    return __uint_as_float(e << 16);
}
__device__ __forceinline__ float bfhi(uint32_t e) {
    return __uint_as_float(e & 0xFFFF0000u);
}

// ------- pass 0: pack tables to bf16x2 (levels 7-15 only, main path) ----
__global__ __launch_bounds__(256) void pack_tables_kernel(
    const float* __restrict__ tables, uint32_t* __restrict__ packed, int base)
{
    const int i = base + blockIdx.x * 256 + threadIdx.x;  // 2 entries/thread
    const f32x4 v = reinterpret_cast<const f32x4*>(tables)[i];
    uint2 o;
    o.x = bf16_rtne_hi(v.x) | (bf16_rtne_hi(v.y) << 16);
    o.y = bf16_rtne_hi(v.z) | (bf16_rtne_hi(v.w) << 16);
    reinterpret_cast<uint2*>(packed)[i] = o;
}

// ---------------- pass 0b-1: dense de-hashed grids ----------------------
template <int S, int LVL>
__device__ __forceinline__ void build_dense_one(
    int r, const float* __restrict__ tables, uint32_t* __restrict__ dst)
{
    const int bz = r % S;
    const int t = r / S;
    const int by = t % S;
    const int bx = t / S;
    const uint32_t h = ((uint32_t)bx ^ ((uint32_t)by * 2654435761u) ^
                        ((uint32_t)bz * 805459861u)) & kMask;
    const float2 src = *reinterpret_cast<const float2*>(
        tables + (((size_t)LVL << 19) + h) * 2);
    dst[r] = bf16_rtne_hi(src.x) | (bf16_rtne_hi(src.y) << 16);
}

__global__ __launch_bounds__(256) void build_dense012_kernel(
    const float* __restrict__ tables, uint32_t* __restrict__ dense)
{
    const int idx = blockIdx.x * 256 + threadIdx.x;
    if (idx >= kNDense) return;
    if (idx < kB1)      build_dense_one<kS0, 0>(idx,       tables, dense);
    else if (idx < kB2) build_dense_one<kS1, 1>(idx - kB1, tables, dense + kB1);
    else                build_dense_one<kS2, 2>(idx - kB2, tables, dense + kB2);
}

__global__ __launch_bounds__(256) void build_denseD_kernel(
    const float* __restrict__ tables, char* __restrict__ ws)
{
    const int g = blockIdx.x * 256 + threadIdx.x;
    if (g >= kV3n + kV4n + kV5n + kV6n) return;
    if (g < kV3n)
        build_dense_one<33, 3>(g, tables, (uint32_t*)(ws + kD3Base));
    else if (g < kV3n + kV4n)
        build_dense_one<41, 4>(g - kV3n, tables, (uint32_t*)(ws + kD4Base));
    else if (g < kV3n + kV4n + kV5n)
        build_dense_one<51, 5>(g - kV3n - kV4n, tables,
                               (uint32_t*)(ws + kD5Base));
    else
        build_dense_one<65, 6>(g - kV3n - kV4n - kV5n, tables,
                               (uint32_t*)(ws + kD6Base));
}

// --------- pass 0b-2: assemble voxel clusters from D (cached reads) -----
// V[(bx*S+by)*S+bz] = 8 corners, c = (dx<<2)|(dy<<1)|dz. Corner coords
// clamped to S-1 (bx==res voxels are never evaluated; clamp avoids OOB).
template <int S>
__device__ __forceinline__ void build_vox_one(
    int v, const uint32_t* __restrict__ D, u32x4* __restrict__ dst)
{
    const int bz = v % S;
    const int t = v / S;
    const int by = t % S;
    const int bx = t / S;
    const int x1 = (bx + 1 < S) ? bx + 1 : S - 1;
    const int y1 = (by + 1 < S) ? by + 1 : S - 1;
    const int z1 = (bz + 1 < S) ? bz + 1 : S - 1;
    u32x4 q0, q1;
    q0.x = D[(bx * S + by) * S + bz];
    q0.y = D[(bx * S + by) * S + z1];
    q0.z = D[(bx * S + y1) * S + bz];
    q0.w = D[(bx * S + y1) * S + z1];
    q1.x = D[(x1 * S + by) * S + bz];
    q1.y = D[(x1 * S + by) * S + z1];
    q1.z = D[(x1 * S + y1) * S + bz];
    q1.w = D[(x1 * S + y1) * S + z1];
    dst[2 * v + 0] = q0;
    dst[2 * v + 1] = q1;
}

__global__ __launch_bounds__(256) void build_vox_kernel(char* __restrict__ ws)
{
    int v = blockIdx.x * 256 + threadIdx.x;
    if (v >= kVAll) return;
    const uint32_t* dense012 = (const uint32_t*)ws;
    if (v < kV0n) {
        build_vox_one<17>(v, dense012, (u32x4*)(ws + kV0Base)); return;
    }
    v -= kV0n;
    if (v < kV1n) {
        build_vox_one<21>(v, dense012 + kB1, (u32x4*)(ws + kV1Base)); return;
    }
    v -= kV1n;
    if (v < kV2n) {
        build_vox_one<26>(v, dense012 + kB2, (u32x4*)(ws + kV2Base)); return;
    }
    v -= kV2n;
    if (v < kV3n) {
        build_vox_one<33>(v, (const uint32_t*)(ws + kD3Base),
                          (u32x4*)(ws + kV3Base)); return;
    }
    v -= kV3n;
    if (v < kV4n) {
        build_vox_one<41>(v, (const uint32_t*)(ws + kD4Base),
                          (u32x4*)(ws + kV4Base)); return;
    }
    v -= kV4n;
    if (v < kV5n) {
        build_vox_one<51>(v, (const uint32_t*)(ws + kD5Base),
                          (u32x4*)(ws + kV5Base)); return;
    }
    v -= kV5n;
    build_vox_one<65>(v, (const uint32_t*)(ws + kD6Base),
                      (u32x4*)(ws + kV6Base));
}

// ------- pass C: levels 7-15 hashed, pinned 2-deep pipeline (round 9) ---
struct PtSt {
    float rx, ry, rz;
    uint32_t sel;
    uint2 p0, p1, p2, p3;
};

__device__ __forceinline__ void issue_pt(
    PtSt& st, const float* __restrict__ x, int n, float r,
    const uint32_t* __restrict__ tab)
{
    const float px = fminf(fmaxf(x[3 * n + 0], 0.f), 1.f);
    const float py = fminf(fmaxf(x[3 * n + 1], 0.f), 1.f);
    const float pz = fminf(fmaxf(x[3 * n + 2], 0.f), 1.f);
    const float tx = px * r, ty = py * r, tz = pz * r;
    const float fx = floorf(tx), fy = floorf(ty), fz = floorf(tz);
    const int bx = (int)fx, by = (int)fy, bz = (int)fz;
    st.rx = tx - fx;  st.ry = ty - fy;  st.rz = tz - fz;
    const uint32_t hy0 = (uint32_t)by * 2654435761u;
    const uint32_t hy1 = (uint32_t)(by + 1) * 2654435761u;
    const uint32_t hz0 = (uint32_t)bz * 805459861u;
    const uint32_t hz1 = (uint32_t)(bz + 1) * 805459861u;
    const uint32_t bxu = (uint32_t)bx, bx1 = bxu + 1u;
    const uint32_t m0 = hy0 ^ hz0, m1 = hy0 ^ hz1;
    const uint32_t m2 = hy1 ^ hz0, m3 = hy1 ^ hz1;
    if ((bx & 1) == 0) {
        const uint32_t h0 = (bxu ^ m0) & kMask;
        const uint32_t h1 = (bxu ^ m1) & kMask;
        const uint32_t h2 = (bxu ^ m2) & kMask;
        const uint32_t h3 = (bxu ^ m3) & kMask;
        st.sel = (h0 & 1u) | ((h1 & 1u) << 1) |
                 ((h2 & 1u) << 2) | ((h3 & 1u) << 3);
        st.p0 = *reinterpret_cast<const uint2*>(tab + (h0 & ~1u));
        st.p1 = *reinterpret_cast<const uint2*>(tab + (h1 & ~1u));
        st.p2 = *reinterpret_cast<const uint2*>(tab + (h2 & ~1u));
        st.p3 = *reinterpret_cast<const uint2*>(tab + (h3 & ~1u));
    } else {
        st.sel = 0u;
        st.p0.x = tab[(bxu ^ m0) & kMask];  st.p0.y = tab[(bx1 ^ m0) & kMask];
        st.p1.x = tab[(bxu ^ m1) & kMask];  st.p1.y = tab[(bx1 ^ m1) & kMask];
        st.p2.x = tab[(bxu ^ m2) & kMask];  st.p2.y = tab[(bx1 ^ m2) & kMask];
        st.p3.x = tab[(bxu ^ m3) & kMask];  st.p3.y = tab[(bx1 ^ m3) & kMask];
    }
}

__device__ __forceinline__ void consume_pt(
    const PtSt& st, uint32_t* __restrict__ w, int n)
{
    const float wx1 = st.rx, wx0 = 1.f - st.rx;
    const float wy1 = st.ry, wy0 = 1.f - st.ry;
    const float wz1 = st.rz, wz0 = 1.f - st.rz;
    const float w0 = wy0 * wz0, w1 = wy0 * wz1;
    const float w2 = wy1 * wz0, w3 = wy1 * wz1;
    const uint32_t e0 = (st.sel & 1u) ? st.p0.y : st.p0.x;
    const uint32_t f0 = (st.sel & 1u) ? st.p0.x : st.p0.y;
    const uint32_t e1 = (st.sel & 2u) ? st.p1.y : st.p1.x;
    const uint32_t f1 = (st.sel & 2u) ? st.p1.x : st.p1.y;
    const uint32_t e2 = (st.sel & 4u) ? st.p2.y : st.p2.x;
    const uint32_t f2 = (st.sel & 4u) ? st.p2.x : st.p2.y;
    const uint32_t e3 = (st.sel & 8u) ? st.p3.y : st.p3.x;
    const uint32_t f3 = (st.sel & 8u) ? st.p3.x : st.p3.y;
    float a0 = 0.f, a1 = 0.f;
    a0 = fmaf(w0, fmaf(wx0, bflo(e0), wx1 * bflo(f0)), a0);
    a1 = fmaf(w0, fmaf(wx0, bfhi(e0), wx1 * bfhi(f0)), a1);
    a0 = fmaf(w1, fmaf(wx0, bflo(e1), wx1 * bflo(f1)), a0);
    a1 = fmaf(w1, fmaf(wx0, bfhi(e1), wx1 * bfhi(f1)), a1);
    a0 = fmaf(w2, fmaf(wx0, bflo(e2), wx1 * bflo(f2)), a0);
    a1 = fmaf(w2, fmaf(wx0, bfhi(e2), wx1 * bfhi(f2)), a1);
    a0 = fmaf(w3, fmaf(wx0, bflo(e3), wx1 * bflo(f3)), a0);
    a1 = fmaf(w3, fmaf(wx0, bfhi(e3), wx1 * bfhi(f3)), a1);
    w[n] = bf16_rtne_hi(a0) | (bf16_rtne_hi(a1) << 16);
}

__global__ __launch_bounds__(256) void fine_kernel(
    const float* __restrict__ x,
    const uint32_t* __restrict__ packed,
    uint32_t* __restrict__ lvl_out)
{
    const int b = blockIdx.x;
    const int level = 7 + (b >> 11);
    const int chunk = b & 2047;

    const float r = c_res[level];
    const uint32_t* __restrict__ tab = packed + (size_t)level * kTableSize;
    uint32_t* __restrict__ w = lvl_out + (size_t)level * kPoints;

    const int n0 = chunk * 1024 + threadIdx.x;

    PtSt A, B;
    issue_pt(A, x, n0 + 0 * 256, r, tab);
    issue_pt(B, x, n0 + 1 * 256, r, tab);
    __builtin_amdgcn_sched_barrier(0);
    consume_pt(A, w, n0 + 0 * 256);
    __builtin_amdgcn_sched_barrier(0);
    issue_pt(A, x, n0 + 2 * 256, r, tab);
    __builtin_amdgcn_sched_barrier(0);
    consume_pt(B, w, n0 + 1 * 256);
    __builtin_amdgcn_sched_barrier(0);
    issue_pt(B, x, n0 + 3 * 256, r, tab);
    __builtin_amdgcn_sched_barrier(0);
    consume_pt(A, w, n0 + 2 * 256);
    __builtin_amdgcn_sched_barrier(0);
    consume_pt(B, w, n0 + 3 * 256);
}

// ------- final: levels 0-6 via V-tables + slices 7-15 -> out [N,32] -----
struct VoxSt {
    float rx, ry, rz;
    u32x4 q0, q1;
};

template <int R>
__device__ __forceinline__ void issue_vox(
    VoxSt& st, const u32x4* __restrict__ V, float px, float py, float pz)
{
    const float r = (float)R;
    const float tx = px * r, ty = py * r, tz = pz * r;
    const float fx = floorf(tx), fy = floorf(ty), fz = floorf(tz);
    const int bx = (int)fx, by = (int)fy, bz = (int)fz;
    st.rx = tx - fx;  st.ry = ty - fy;  st.rz = tz - fz;
    constexpr int S = R + 1;
    const int idx = (bx * S + by) * S + bz;
    st.q0 = V[2 * idx + 0];
    st.q1 = V[2 * idx + 1];
}

__device__ __forceinline__ uint32_t consume_vox(const VoxSt& st)
{
    const float wx1 = st.rx, wx0 = 1.f - st.rx;
    const float wy1 = st.ry, wy0 = 1.f - st.ry;
    const float wz1 = st.rz, wz0 = 1.f - st.rz;
    float a0 = 0.f, a1 = 0.f;
    a0 = fmaf(wx0 * wy0 * wz0, bflo(st.q0.x), a0);
    a1 = fmaf(wx0 * wy0 * wz0, bfhi(st.q0.x), a1);
    a0 = fmaf(wx0 * wy0 * wz1, bflo(st.q0.y), a0);
    a1 = fmaf(wx0 * wy0 * wz1, bfhi(st.q0.y), a1);
    a0 = fmaf(wx0 * wy1 * wz0, bflo(st.q0.z), a0);
    a1 = fmaf(wx0 * wy1 * wz0, bfhi(st.q0.z), a1);
    a0 = fmaf(wx0 * wy1 * wz1, bflo(st.q0.w), a0);
    a1 = fmaf(wx0 * wy1 * wz1, bfhi(st.q0.w), a1);
    a0 = fmaf(wx1 * wy0 * wz0, bflo(st.q1.x), a0);
    a1 = fmaf(wx1 * wy0 * wz0, bfhi(st.q1.x), a1);
    a0 = fmaf(wx1 * wy0 * wz1, bflo(st.q1.y), a0);
    a1 = fmaf(wx1 * wy0 * wz1, bfhi(st.q1.y), a1);
    a0 = fmaf(wx1 * wy1 * wz0, bflo(st.q1.z), a0);
    a1 = fmaf(wx1 * wy1 * wz0, bfhi(st.q1.z), a1);
    a0 = fmaf(wx1 * wy1 * wz1, bflo(st.q1.w), a0);
    a1 = fmaf(wx1 * wy1 * wz1, bfhi(st.q1.w), a1);
    return bf16_rtne_hi(a0) | (bf16_rtne_hi(a1) << 16);
}

__global__ __launch_bounds__(256) void final_kernel(
    const float* __restrict__ x, const char* __restrict__ ws,
    const uint32_t* __restrict__ lvl_out, float* __restrict__ out)
{
    const int n = blockIdx.x * 256 + threadIdx.x;
    const float px = fminf(fmaxf(x[3 * n + 0], 0.f), 1.f);
    const float py = fminf(fmaxf(x[3 * n + 1], 0.f), 1.f);
    const float pz = fminf(fmaxf(x[3 * n + 2], 0.f), 1.f);

    // coalesced fine-slice reads (levels 7-15), issued first
    uint32_t u7  = lvl_out[(size_t)7  * kPoints + n];
    uint32_t u8  = lvl_out[(size_t)8  * kPoints + n];
    uint32_t u9  = lvl_out[(size_t)9  * kPoints + n];
    uint32_t u10 = lvl_out[(size_t)10 * kPoints + n];
    uint32_t u11 = lvl_out[(size_t)11 * kPoints + n];
    uint32_t u12 = lvl_out[(size_t)12 * kPoints + n];
    uint32_t u13 = lvl_out[(size_t)13 * kPoints + n];
    uint32_t u14 = lvl_out[(size_t)14 * kPoints + n];
    uint32_t u15 = lvl_out[(size_t)15 * kPoints + n];

    // 14 gathers, all issued before any consume (single BB, pinned)
    VoxSt s0, s1, s2, s3, s4, s5, s6;
    issue_vox<16>(s0, (const u32x4*)(ws + kV0Base), px, py, pz);
    issue_vox<20>(s1, (const u32x4*)(ws + kV1Base), px, py, pz);
    issue_vox<25>(s2, (const u32x4*)(ws + kV2Base), px, py, pz);
    issue_vox<32>(s3, (const u32x4*)(ws + kV3Base), px, py, pz);
    issue_vox<40>(s4, (const u32x4*)(ws + kV4Base), px, py, pz);
    issue_vox<50>(s5, (const u32x4*)(ws + kV5Base), px, py, pz);
    issue_vox<64>(s6, (const u32x4*)(ws + kV6Base), px, py, pz);
    __builtin_amdgcn_sched_barrier(0);

    const uint32_t w0 = consume_vox(s0);
    const uint32_t w1 = consume_vox(s1);
    const uint32_t w2 = consume_vox(s2);
    const uint32_t w3 = consume_vox(s3);
    const uint32_t w4 = consume_vox(s4);
    const uint32_t w5 = consume_vox(s5);
    const uint32_t w6 = consume_vox(s6);

    float4* o4 = reinterpret_cast<float4*>(out + (size_t)n * 32);
    o4[0] = make_float4(bflo(w0),  bfhi(w0),  bflo(w1),  bfhi(w1));
    o4[1] = make_float4(bflo(w2),  bfhi(w2),  bflo(w3),  bfhi(w3));
    o4[2] = make_float4(bflo(w4),  bfhi(w4),  bflo(w5),  bfhi(w5));
    o4[3] = make_float4(bflo(w6),  bfhi(w6),  bflo(u7),  bfhi(u7));
    o4[4] = make_float4(bflo(u8),  bfhi(u8),  bflo(u9),  bfhi(u9));
    o4[5] = make_float4(bflo(u10), bfhi(u10), bflo(u11), bfhi(u11));
    o4[6] = make_float4(bflo(u12), bfhi(u12), bflo(u13), bfhi(u13));
    o4[7] = make_float4(bflo(u14), bfhi(u14), bflo(u15), bfhi(u15));
}

// ---------------- fallbacks (round-0/round-2 proven paths) --------------
__device__ __forceinline__ void eval_level(
    float px, float py, float pz, float r,
    const uint32_t* __restrict__ tab, float& a0, float& a1)
{
    const float tx = px * r, ty = py * r, tz = pz * r;
    const float fx = floorf(tx), fy = floorf(ty), fz = floorf(tz);
    const int bx = (int)fx, by = (int)fy, bz = (int)fz;
    const float rx = tx - fx, ry = ty - fy, rz = tz - fz;

    const uint32_t hx0 = (uint32_t)bx;
    const uint32_t hx1 = (uint32_t)(bx + 1);
    const uint32_t hy0 = (uint32_t)by * 2654435761u;
    const uint32_t hy1 = (uint32_t)(by + 1) * 2654435761u;
    const uint32_t hz0 = (uint32_t)bz * 805459861u;
    const uint32_t hz1 = (uint32_t)(bz + 1) * 805459861u;

    const float wx1 = rx, wx0 = 1.0f - rx;
    const float wy1 = ry, wy0 = 1.0f - ry;
    const float wz1 = rz, wz0 = 1.0f - rz;

    a0 = 0.0f; a1 = 0.0f;
#pragma unroll
    for (int c = 0; c < 8; ++c) {
        const uint32_t h = (((c & 4) ? hx1 : hx0) ^
                            ((c & 2) ? hy1 : hy0) ^
                            ((c & 1) ? hz1 : hz0)) & kMask;
        const uint32_t e = tab[h];
        const float w = ((c & 4) ? wx1 : wx0) *
                        ((c & 2) ? wy1 : wy0) *
                        ((c & 1) ? wz1 : wz0);
        a0 = fmaf(w, bflo(e), a0);
        a1 = fmaf(w, bfhi(e), a1);
    }
}

__global__ __launch_bounds__(256) void direct_kernel(
    const float* __restrict__ x,
    const float* __restrict__ tables,
    float* __restrict__ out)
{
    const int n = blockIdx.x * 256 + threadIdx.x;
    float px = fminf(fmaxf(x[3 * n + 0], 0.0f), 1.0f);
    float py = fminf(fmaxf(x[3 * n + 1], 0.0f), 1.0f);
    float pz = fminf(fmaxf(x[3 * n + 2], 0.0f), 1.0f);

    const float res_tab[kLevels] = {
        16.f, 20.f, 25.f, 32.f, 40.f, 50.f, 64.f, 80.f,
        101.f, 128.f, 161.f, 203.f, 256.f, 322.f, 406.f, 512.f};

    float acc[2 * kLevels];
#pragma unroll
    for (int l = 0; l < kLevels; ++l) {
        const float r = res_tab[l];
        const float tx = px * r, ty = py * r, tz = pz * r;
        const float fx = floorf(tx), fy = floorf(ty), fz = floorf(tz);
        const int bx = (int)fx, by = (int)fy, bz = (int)fz;
        const float rx = tx - fx, ry = ty - fy, rz = tz - fz;
        const uint32_t hx0 = (uint32_t)bx;
        const uint32_t hx1 = (uint32_t)(bx + 1);
        const uint32_t hy0 = (uint32_t)by * 2654435761u;
        const uint32_t hy1 = (uint32_t)(by + 1) * 2654435761u;
        const uint32_t hz0 = (uint32_t)bz * 805459861u;
        const uint32_t hz1 = (uint32_t)(bz + 1) * 805459861u;
        const float wx1 = rx, wx0 = 1.0f - rx;
        const float wy1 = ry, wy0 = 1.0f - ry;
        const float wz1 = rz, wz0 = 1.0f - rz;
        const float2* __restrict__ tab =
            reinterpret_cast<const float2*>(tables) + (size_t)l * kTableSize;
        float a0 = 0.0f, a1 = 0.0f;
#pragma unroll
        for (int c = 0; c < 8; ++c) {
            const uint32_t h = (((c & 4) ? hx1 : hx0) ^
                                ((c & 2) ? hy1 : hy0) ^
                                ((c & 1) ? hz1 : hz0)) & kMask;
            const float2 e = tab[h];
            const float w = ((c & 4) ? wx1 : wx0) *
                            ((c & 2) ? wy1 : wy0) *
                            ((c & 1) ? wz1 : wz0);
            a0 = fmaf(w, e.x, a0);
            a1 = fmaf(w, e.y, a1);
        }
        acc[2 * l + 0] = a0;
        acc[2 * l + 1] = a1;
    }
    float4* o4 = reinterpret_cast<float4*>(out + (size_t)n * (2 * kLevels));
#pragma unroll
    for (int kq = 0; kq < 8; ++kq) {
        o4[kq] = make_float4(acc[4 * kq + 0], acc[4 * kq + 1],
                             acc[4 * kq + 2], acc[4 * kq + 3]);
    }
}

__global__ __launch_bounds__(256) void direct_packed_kernel(
    const float* __restrict__ x,
    const uint32_t* __restrict__ packed,
    float* __restrict__ out)
{
    const int n = blockIdx.x * 256 + threadIdx.x;
    float px = fminf(fmaxf(x[3 * n + 0], 0.0f), 1.0f);
    float py = fminf(fmaxf(x[3 * n + 1], 0.0f), 1.0f);
    float pz = fminf(fmaxf(x[3 * n + 2], 0.0f), 1.0f);

    const float res_tab[kLevels] = {
        16.f, 20.f, 25.f, 32.f, 40.f, 50.f, 64.f, 80.f,
        101.f, 128.f, 161.f, 203.f, 256.f, 322.f, 406.f, 512.f};

    float acc[2 * kLevels];
#pragma unroll
    for (int l = 0; l < kLevels; ++l) {
        float a0, a1;
        eval_level(px, py, pz, res_tab[l],
                   packed + (size_t)l * kTableSize, a0, a1);
        acc[2 * l + 0] = a0;
        acc[2 * l + 1] = a1;
    }
    float4* o4 = reinterpret_cast<float4*>(out + (size_t)n * (2 * kLevels));
#pragma unroll
    for (int kq = 0; kq < 8; ++kq) {
        o4[kq] = make_float4(acc[4 * kq + 0], acc[4 * kq + 1],
                             acc[4 * kq + 2], acc[4 * kq + 3]);
    }
}

extern "C" void kernel_launch(void* const* d_in, const int* in_sizes, int n_in,
                              void* d_out, int out_size, void* d_ws, size_t ws_size,
                              hipStream_t stream) {
    const float* x = (const float*)d_in[0];       // [2^21, 3] f32
    const float* tables = (const float*)d_in[1];  // [16, 2^19, 2] f32
    float* out = (float*)d_out;                   // [2^21, 32] f32

    if (ws_size >= kPackedBytes + kLvlOutBytes) {
        char* ws = (char*)d_ws;
        uint32_t* packed = (uint32_t*)ws;
        uint32_t* lvl_out = (uint32_t*)(ws + kPackedBytes);
        uint32_t* dense012 = (uint32_t*)ws;  // overlays packed[0] (unused)

        // pack only levels 7-15 (fine path).
        hipLaunchKernelGGL(pack_tables_kernel,
                           dim3((9 << 19) / 2 / 256), dim3(256),
                           0, stream, tables, packed, (7 << 19) / 2);
        hipLaunchKernelGGL(build_dense012_kernel,
                           dim3((kNDense + 255) / 256), dim3(256),
                           0, stream, tables, dense012);
        hipLaunchKernelGGL(build_denseD_kernel,
                           dim3((kV3n + kV4n + kV5n + kV6n + 255) / 256),
                           dim3(256), 0, stream, tables, ws);
        hipLaunchKernelGGL(build_vox_kernel,
                           dim3((kVAll + 255) / 256), dim3(256),
                           0, stream, ws);
        // pass C: levels 7-15 -> lvl_out slices 7-15 (slices 0-1 hold V6)
        hipLaunchKernelGGL(fine_kernel, dim3(9 * 2048), dim3(256),
                           0, stream, x, packed, lvl_out);
        // final: levels 0-6 (V-tables) + slices 7-15 -> out [N,32]
        hipLaunchKernelGGL(final_kernel, dim3(kPoints / 256), dim3(256),
                           0, stream, x, (const char*)ws, lvl_out, out);
    } else if (ws_size >= kPackedBytes) {
        uint32_t* packed = (uint32_t*)d_ws;
        hipLaunchKernelGGL(pack_tables_kernel,
                           dim3((kLevels * kTableSize / 2) / 256), dim3(256),
                           0, stream, tables, packed, 0);
        hipLaunchKernelGGL(direct_packed_kernel, dim3(kPoints / 256), dim3(256),
                           0, stream, x, packed, out);
    } else {
        hipLaunchKernelGGL(direct_kernel, dim3(kPoints / 256), dim3(256),
                           0, stream, x, tables, out);
    }
}

// Round 14
// 556.829 us; speedup vs baseline: 1.0438x; 1.0438x over previous
//
#include <hip/hip_runtime.h>
#include <stdint.h>

// HashEmbedder (Instant-NGP multires hash grid), 16 levels, F=2, T=2^19,
// N = 2^21 points.
//
// Round-14 = REVERT to round-12 (557us, best). Round-13's fusion regressed
// (+24us): all VMEM requests share the TA pipe additively (coalesced
// ~1 req/cyc/CU, divergent gathers ~0.55 req/cyc/CU); fusing moved
// levels 0-2 from free LDS reads to 0.55-rate gathers and concentrated
// 31 req/pt in one kernel. The r12 split places each level class on its
// cheapest resource:
//   levels 0-2 : LDS-staged dense tables (127 KB, gathers free of TA).
//   levels 3-6 : voxel-cluster tables (2 dwordx4 = 1 line per pt/level),
//                pinned 2-deep pipeline.
//   levels 7-15: hashed, level-at-a-time (per-XCD L2 holds one 2MB
//                table), even-bx pairing (6 req/pt = provable minimum),
//                pinned 2-deep pipeline. 341us = divergent-gather
//                request ceiling (~0.55 req/cyc/CU, confirmed by four
//                independent structures incl. 32-deep inline-asm MLP).
//   untile     : level-major bf16x2 -> [N][32] f32, ~84% HBM BW.

constexpr int kLevels = 16;
constexpr int kPoints = 1 << 21;
constexpr uint32_t kTableSize = 1u << 19;
constexpr uint32_t kMask = kTableSize - 1u;
constexpr size_t kPackedBytes = (size_t)kLevels * kTableSize * 4;  // 32 MB
constexpr size_t kLvlOutBytes = (size_t)kLevels * kPoints * 4;     // 128 MB

typedef float f32x4 __attribute__((ext_vector_type(4)));
typedef uint32_t u32x4 __attribute__((ext_vector_type(4)));

// dense coarse (levels 0-2): entry counts and bases (uint32 units)
constexpr int kS0 = 17, kS1 = 21, kS2 = 26;            // res+1
constexpr int kN0 = kS0 * kS0 * kS0;                   // 4913
constexpr int kN1 = kS1 * kS1 * kS1;                   // 9261
constexpr int kN2 = kS2 * kS2 * kS2;                   // 17576
constexpr int kB1 = kN0, kB2 = kN0 + kN1;              // 4913, 14174
constexpr int kNDense = kN0 + kN1 + kN2;               // 31750

// voxel-cluster tables (levels 3-6): S^3 slots x 32B, S = res+1
constexpr int kV3n = 33 * 33 * 33;   // 35937
constexpr int kV4n = 41 * 41 * 41;   // 68921
constexpr int kV5n = 51 * 51 * 51;   // 132651
constexpr int kV6n = 65 * 65 * 65;   // 274625
constexpr int kVTot = kV3n + kV4n + kV5n + kV6n;       // 512134
// byte offsets inside ws (all scratch in freed packed[0..6] region, 14 MB)
constexpr size_t kV3Base = 131072;                         // after dense012
constexpr size_t kV4Base = kV3Base + (size_t)kV3n * 32;    // 1281056
constexpr size_t kV5Base = kV4Base + (size_t)kV4n * 32;    // 3486528
// V5 end = 7731360. V6 (8.8MB) lives in lvl_out slice 7 (+0.4MB of 8):
// written by build, read by mid, clobbered later by fine (stream order).
constexpr size_t kV6Base = kPackedBytes + (size_t)7 * kPoints * 4;
// dense bf16x2 grids D3-6 (S^3 x 4B), after V5:
constexpr size_t kD3Base = 7731456;                        // 256-aligned
constexpr size_t kD4Base = 7875328;   // D3 end 7875204
constexpr size_t kD5Base = 8151296;   // D4 end 8151012
constexpr size_t kD6Base = 8681984;   // D5 end 8681900
// D6 end = 9780484 < 14680064 (freed packed region). OK.

// floor(16 * b^i), b = exp(ln(32)/15) in f64 (boundary levels round up).
__constant__ float c_res[kLevels] = {
    16.f, 20.f, 25.f, 32.f, 40.f, 50.f, 64.f, 80.f,
    101.f, 128.f, 161.f, 203.f, 256.f, 322.f, 406.f, 512.f};

__device__ __forceinline__ uint32_t bf16_rtne_hi(float f) {
    uint32_t u = __float_as_uint(f);
    return (u + 0x7FFFu + ((u >> 16) & 1u)) >> 16;
}
__device__ __forceinline__ float bflo(uint32_t e) {
    return __uint_as_float(e << 16);
}
__device__ __forceinline__ float bfhi(uint32_t e) {
    return __uint_as_float(e & 0xFFFF0000u);
}

// ------- pass 0: pack tables to bf16x2 (levels 7-15 only, main path) ----
__global__ __launch_bounds__(256) void pack_tables_kernel(
    const float* __restrict__ tables, uint32_t* __restrict__ packed, int base)
{
    const int i = base + blockIdx.x * 256 + threadIdx.x;  // 2 entries/thread
    const f32x4 v = reinterpret_cast<const f32x4*>(tables)[i];
    uint2 o;
    o.x = bf16_rtne_hi(v.x) | (bf16_rtne_hi(v.y) << 16);
    o.y = bf16_rtne_hi(v.z) | (bf16_rtne_hi(v.w) << 16);
    reinterpret_cast<uint2*>(packed)[i] = o;
}

// ---------------- pass 0b-1: dense de-hashed tables, levels 0-2 --------
template <int S, int LVL>
__device__ __forceinline__ void build_dense_one(
    int r, const float* __restrict__ tables, uint32_t* __restrict__ dst)
{
    const int bz = r % S;
    const int t = r / S;
    const int by = t % S;
    const int bx = t / S;
    const uint32_t h = ((uint32_t)bx ^ ((uint32_t)by * 2654435761u) ^
                        ((uint32_t)bz * 805459861u)) & kMask;
    const float2 src = *reinterpret_cast<const float2*>(
        tables + (((size_t)LVL << 19) + h) * 2);
    dst[r] = bf16_rtne_hi(src.x) | (bf16_rtne_hi(src.y) << 16);
}

__global__ __launch_bounds__(256) void build_dense012_kernel(
    const float* __restrict__ tables, uint32_t* __restrict__ dense)
{
    const int idx = blockIdx.x * 256 + threadIdx.x;
    if (idx >= kNDense) return;
    if (idx < kB1)      build_dense_one<kS0, 0>(idx,       tables, dense);
    else if (idx < kB2) build_dense_one<kS1, 1>(idx - kB1, tables, dense + kB1);
    else                build_dense_one<kS2, 2>(idx - kB2, tables, dense + kB2);
}

// --------- pass 0b-2a: dense bf16x2 grids D3-6 (1 gather per corner) ----
__global__ __launch_bounds__(256) void build_denseD_kernel(
    const float* __restrict__ tables, char* __restrict__ ws)
{
    const int g = blockIdx.x * 256 + threadIdx.x;
    if (g >= kVTot) return;
    if (g < kV3n)
        build_dense_one<33, 3>(g, tables, (uint32_t*)(ws + kD3Base));
    else if (g < kV3n + kV4n)
        build_dense_one<41, 4>(g - kV3n, tables, (uint32_t*)(ws + kD4Base));
    else if (g < kV3n + kV4n + kV5n)
        build_dense_one<51, 5>(g - kV3n - kV4n, tables,
                               (uint32_t*)(ws + kD5Base));
    else
        build_dense_one<65, 6>(g - kV3n - kV4n - kV5n, tables,
                               (uint32_t*)(ws + kD6Base));
}

// --------- pass 0b-2b: assemble voxel clusters from D (cached reads) ----
// V[(bx*S+by)*S+bz] = 8 corners, c = (dx<<2)|(dy<<1)|dz. Corner coords
// clamped to S-1 (voxels with bx==res never evaluated; clamp avoids OOB).
template <int S>
__device__ __forceinline__ void build_vox_one(
    int v, const uint32_t* __restrict__ D, u32x4* __restrict__ dst)
{
    const int bz = v % S;
    const int t = v / S;
    const int by = t % S;
    const int bx = t / S;
    const int x1 = (bx + 1 < S) ? bx + 1 : S - 1;
    const int y1 = (by + 1 < S) ? by + 1 : S - 1;
    const int z1 = (bz + 1 < S) ? bz + 1 : S - 1;
    u32x4 q0, q1;
    q0.x = D[(bx * S + by) * S + bz];
    q0.y = D[(bx * S + by) * S + z1];
    q0.z = D[(bx * S + y1) * S + bz];
    q0.w = D[(bx * S + y1) * S + z1];
    q1.x = D[(x1 * S + by) * S + bz];
    q1.y = D[(x1 * S + by) * S + z1];
    q1.z = D[(x1 * S + y1) * S + bz];
    q1.w = D[(x1 * S + y1) * S + z1];
    dst[2 * v + 0] = q0;
    dst[2 * v + 1] = q1;
}

__global__ __launch_bounds__(256) void build_vox_kernel(char* __restrict__ ws)
{
    const int v = blockIdx.x * 256 + threadIdx.x;
    if (v >= kVTot) return;
    if (v < kV3n)
        build_vox_one<33>(v, (const uint32_t*)(ws + kD3Base),
                          (u32x4*)(ws + kV3Base));
    else if (v < kV3n + kV4n)
        build_vox_one<41>(v - kV3n, (const uint32_t*)(ws + kD4Base),
                          (u32x4*)(ws + kV4Base));
    else if (v < kV3n + kV4n + kV5n)
        build_vox_one<51>(v - kV3n - kV4n, (const uint32_t*)(ws + kD5Base),
                          (u32x4*)(ws + kV5Base));
    else
        build_vox_one<65>(v - kV3n - kV4n - kV5n,
                          (const uint32_t*)(ws + kD6Base),
                          (u32x4*)(ws + kV6Base));
}

// ---------------- pass A: levels 0-2 via LDS dense tables ----------------
template <int S, int BASE, int LVL>
__device__ __forceinline__ void eval_coarse(
    const uint32_t* __restrict__ lds, float px, float py, float pz, float r,
    uint32_t* __restrict__ lvl_out, int n)
{
    const float tx = px * r, ty = py * r, tz = pz * r;
    const float fx = floorf(tx), fy = floorf(ty), fz = floorf(tz);
    const int bx = (int)fx, by = (int)fy, bz = (int)fz;
    const float rx = tx - fx, ry = ty - fy, rz = tz - fz;
    const int c = BASE + (bx * S + by) * S + bz;
    const uint32_t e000 = lds[c],             e001 = lds[c + 1];
    const uint32_t e010 = lds[c + S],         e011 = lds[c + S + 1];
    const uint32_t e100 = lds[c + S * S],     e101 = lds[c + S * S + 1];
    const uint32_t e110 = lds[c + S * S + S], e111 = lds[c + S * S + S + 1];
    const float wx1 = rx, wx0 = 1.f - rx;
    const float wy1 = ry, wy0 = 1.f - ry;
    const float wz1 = rz, wz0 = 1.f - rz;
    float a0 = 0.f, a1 = 0.f;
    a0 = fmaf(wx0 * wy0 * wz0, bflo(e000), a0);
    a1 = fmaf(wx0 * wy0 * wz0, bfhi(e000), a1);
    a0 = fmaf(wx0 * wy0 * wz1, bflo(e001), a0);
    a1 = fmaf(wx0 * wy0 * wz1, bfhi(e001), a1);
    a0 = fmaf(wx0 * wy1 * wz0, bflo(e010), a0);
    a1 = fmaf(wx0 * wy1 * wz0, bfhi(e010), a1);
    a0 = fmaf(wx0 * wy1 * wz1, bflo(e011), a0);
    a1 = fmaf(wx0 * wy1 * wz1, bfhi(e011), a1);
    a0 = fmaf(wx1 * wy0 * wz0, bflo(e100), a0);
    a1 = fmaf(wx1 * wy0 * wz0, bfhi(e100), a1);
    a0 = fmaf(wx1 * wy0 * wz1, bflo(e101), a0);
    a1 = fmaf(wx1 * wy0 * wz1, bfhi(e101), a1);
    a0 = fmaf(wx1 * wy1 * wz0, bflo(e110), a0);
    a1 = fmaf(wx1 * wy1 * wz0, bfhi(e110), a1);
    a0 = fmaf(wx1 * wy1 * wz1, bflo(e111), a0);
    a1 = fmaf(wx1 * wy1 * wz1, bfhi(e111), a1);
    lvl_out[(size_t)LVL * kPoints + n] =
        bf16_rtne_hi(a0) | (bf16_rtne_hi(a1) << 16);
}

__global__ __launch_bounds__(512) void coarse_kernel(
    const float* __restrict__ x, const uint32_t* __restrict__ dense,
    uint32_t* __restrict__ lvl_out)
{
    __shared__ uint32_t s_tab[kNDense];  // 127000 B
    for (int i = threadIdx.x; i < kNDense; i += 512) s_tab[i] = dense[i];
    __syncthreads();

    const int n0 = blockIdx.x * 2048 + threadIdx.x;
#pragma unroll
    for (int k = 0; k < 4; ++k) {
        const int n = n0 + k * 512;
        const float px = fminf(fmaxf(x[3 * n + 0], 0.0f), 1.0f);
        const float py = fminf(fmaxf(x[3 * n + 1], 0.0f), 1.0f);
        const float pz = fminf(fmaxf(x[3 * n + 2], 0.0f), 1.0f);
        eval_coarse<kS0, 0,   0>(s_tab, px, py, pz, 16.f, lvl_out, n);
        eval_coarse<kS1, kB1, 1>(s_tab, px, py, pz, 20.f, lvl_out, n);
        eval_coarse<kS2, kB2, 2>(s_tab, px, py, pz, 25.f, lvl_out, n);
    }
}

// ------- pass B: levels 3-6 via voxel clusters, pinned 2-deep pipe ------
struct MidSt {
    float rx, ry, rz;
    u32x4 q0, q1;      // 8 corner entries (c = (dx<<2)|(dy<<1)|dz)
};

template <int R>
__device__ __forceinline__ void issue_mid(
    MidSt& st, const u32x4* __restrict__ V, float px, float py, float pz)
{
    const float r = (float)R;
    const float tx = px * r, ty = py * r, tz = pz * r;
    const float fx = floorf(tx), fy = floorf(ty), fz = floorf(tz);
    const int bx = (int)fx, by = (int)fy, bz = (int)fz;
    st.rx = tx - fx;  st.ry = ty - fy;  st.rz = tz - fz;
    constexpr int S = R + 1;
    const int idx = (bx * S + by) * S + bz;
    st.q0 = V[2 * idx + 0];
    st.q1 = V[2 * idx + 1];
}

__device__ __forceinline__ void consume_mid(
    const MidSt& st, uint32_t* __restrict__ dst)
{
    const float wx1 = st.rx, wx0 = 1.f - st.rx;
    const float wy1 = st.ry, wy0 = 1.f - st.ry;
    const float wz1 = st.rz, wz0 = 1.f - st.rz;
    float a0 = 0.f, a1 = 0.f;
    a0 = fmaf(wx0 * wy0 * wz0, bflo(st.q0.x), a0);
    a1 = fmaf(wx0 * wy0 * wz0, bfhi(st.q0.x), a1);
    a0 = fmaf(wx0 * wy0 * wz1, bflo(st.q0.y), a0);
    a1 = fmaf(wx0 * wy0 * wz1, bfhi(st.q0.y), a1);
    a0 = fmaf(wx0 * wy1 * wz0, bflo(st.q0.z), a0);
    a1 = fmaf(wx0 * wy1 * wz0, bfhi(st.q0.z), a1);
    a0 = fmaf(wx0 * wy1 * wz1, bflo(st.q0.w), a0);
    a1 = fmaf(wx0 * wy1 * wz1, bfhi(st.q0.w), a1);
    a0 = fmaf(wx1 * wy0 * wz0, bflo(st.q1.x), a0);
    a1 = fmaf(wx1 * wy0 * wz0, bfhi(st.q1.x), a1);
    a0 = fmaf(wx1 * wy0 * wz1, bflo(st.q1.y), a0);
    a1 = fmaf(wx1 * wy0 * wz1, bfhi(st.q1.y), a1);
    a0 = fmaf(wx1 * wy1 * wz0, bflo(st.q1.z), a0);
    a1 = fmaf(wx1 * wy1 * wz0, bfhi(st.q1.z), a1);
    a0 = fmaf(wx1 * wy1 * wz1, bflo(st.q1.w), a0);
    a1 = fmaf(wx1 * wy1 * wz1, bfhi(st.q1.w), a1);
    *dst = bf16_rtne_hi(a0) | (bf16_rtne_hi(a1) << 16);
}

template <int R, int LVL>
__device__ __forceinline__ void mid_level(
    const float* __restrict__ x, const u32x4* __restrict__ V,
    uint32_t* __restrict__ lvl_out, int n0)
{
    uint32_t* __restrict__ w = lvl_out + (size_t)LVL * kPoints;
    const float px0 = fminf(fmaxf(x[3 * (n0 + 0 * 256) + 0], 0.f), 1.f);
    const float py0 = fminf(fmaxf(x[3 * (n0 + 0 * 256) + 1], 0.f), 1.f);
    const float pz0 = fminf(fmaxf(x[3 * (n0 + 0 * 256) + 2], 0.f), 1.f);
    const float px1 = fminf(fmaxf(x[3 * (n0 + 1 * 256) + 0], 0.f), 1.f);
    const float py1 = fminf(fmaxf(x[3 * (n0 + 1 * 256) + 1], 0.f), 1.f);
    const float pz1 = fminf(fmaxf(x[3 * (n0 + 1 * 256) + 2], 0.f), 1.f);
    const float px2 = fminf(fmaxf(x[3 * (n0 + 2 * 256) + 0], 0.f), 1.f);
    const float py2 = fminf(fmaxf(x[3 * (n0 + 2 * 256) + 1], 0.f), 1.f);
    const float pz2 = fminf(fmaxf(x[3 * (n0 + 2 * 256) + 2], 0.f), 1.f);
    const float px3 = fminf(fmaxf(x[3 * (n0 + 3 * 256) + 0], 0.f), 1.f);
    const float py3 = fminf(fmaxf(x[3 * (n0 + 3 * 256) + 1], 0.f), 1.f);
    const float pz3 = fminf(fmaxf(x[3 * (n0 + 3 * 256) + 2], 0.f), 1.f);
    __builtin_amdgcn_sched_barrier(0);

    MidSt A, B;
    issue_mid<R>(A, V, px0, py0, pz0);
    issue_mid<R>(B, V, px1, py1, pz1);
    __builtin_amdgcn_sched_barrier(0);
    consume_mid(A, &w[n0 + 0 * 256]);
    __builtin_amdgcn_sched_barrier(0);
    issue_mid<R>(A, V, px2, py2, pz2);
    __builtin_amdgcn_sched_barrier(0);
    consume_mid(B, &w[n0 + 1 * 256]);
    __builtin_amdgcn_sched_barrier(0);
    issue_mid<R>(B, V, px3, py3, pz3);
    __builtin_amdgcn_sched_barrier(0);
    consume_mid(A, &w[n0 + 2 * 256]);
    __builtin_amdgcn_sched_barrier(0);
    consume_mid(B, &w[n0 + 3 * 256]);
}

__global__ __launch_bounds__(256) void mid_kernel(
    const float* __restrict__ x, const char* __restrict__ ws,
    uint32_t* __restrict__ lvl_out)
{
    const int b = blockIdx.x;
    const int sub = b >> 11;                 // 0..3 -> level 3..6
    const int chunk = b & 2047;
    const int n0 = chunk * 1024 + threadIdx.x;
    if (sub == 0)
        mid_level<32, 3>(x, (const u32x4*)(ws + kV3Base), lvl_out, n0);
    else if (sub == 1)
        mid_level<40, 4>(x, (const u32x4*)(ws + kV4Base), lvl_out, n0);
    else if (sub == 2)
        mid_level<50, 5>(x, (const u32x4*)(ws + kV5Base), lvl_out, n0);
    else
        mid_level<64, 6>(x, (const u32x4*)(ws + kV6Base), lvl_out, n0);
}

// ------- pass C: levels 7-15 hashed, pinned 2-deep pipeline (round 9) ---
struct PtSt {
    float rx, ry, rz;
    uint32_t sel;              // bit j = half-selector for corner pair j
    uint2 p0, p1, p2, p3;      // corner-pair entries (elo/ehi encoded)
};

__device__ __forceinline__ void issue_pt(
    PtSt& st, const float* __restrict__ x, int n, float r,
    const uint32_t* __restrict__ tab)
{
    const float px = fminf(fmaxf(x[3 * n + 0], 0.f), 1.f);
    const float py = fminf(fmaxf(x[3 * n + 1], 0.f), 1.f);
    const float pz = fminf(fmaxf(x[3 * n + 2], 0.f), 1.f);
    const float tx = px * r, ty = py * r, tz = pz * r;
    const float fx = floorf(tx), fy = floorf(ty), fz = floorf(tz);
    const int bx = (int)fx, by = (int)fy, bz = (int)fz;
    st.rx = tx - fx;  st.ry = ty - fy;  st.rz = tz - fz;
    const uint32_t hy0 = (uint32_t)by * 2654435761u;
    const uint32_t hy1 = (uint32_t)(by + 1) * 2654435761u;
    const uint32_t hz0 = (uint32_t)bz * 805459861u;
    const uint32_t hz1 = (uint32_t)(bz + 1) * 805459861u;
    const uint32_t bxu = (uint32_t)bx, bx1 = bxu + 1u;
    const uint32_t m0 = hy0 ^ hz0, m1 = hy0 ^ hz1;
    const uint32_t m2 = hy1 ^ hz0, m3 = hy1 ^ hz1;
    if ((bx & 1) == 0) {
        const uint32_t h0 = (bxu ^ m0) & kMask;
        const uint32_t h1 = (bxu ^ m1) & kMask;
        const uint32_t h2 = (bxu ^ m2) & kMask;
        const uint32_t h3 = (bxu ^ m3) & kMask;
        st.sel = (h0 & 1u) | ((h1 & 1u) << 1) |
                 ((h2 & 1u) << 2) | ((h3 & 1u) << 3);
        st.p0 = *reinterpret_cast<const uint2*>(tab + (h0 & ~1u));
        st.p1 = *reinterpret_cast<const uint2*>(tab + (h1 & ~1u));
        st.p2 = *reinterpret_cast<const uint2*>(tab + (h2 & ~1u));
        st.p3 = *reinterpret_cast<const uint2*>(tab + (h3 & ~1u));
    } else {
        st.sel = 0u;
        st.p0.x = tab[(bxu ^ m0) & kMask];  st.p0.y = tab[(bx1 ^ m0) & kMask];
        st.p1.x = tab[(bxu ^ m1) & kMask];  st.p1.y = tab[(bx1 ^ m1) & kMask];
        st.p2.x = tab[(bxu ^ m2) & kMask];  st.p2.y = tab[(bx1 ^ m2) & kMask];
        st.p3.x = tab[(bxu ^ m3) & kMask];  st.p3.y = tab[(bx1 ^ m3) & kMask];
    }
}

__device__ __forceinline__ void consume_pt(
    const PtSt& st, uint32_t* __restrict__ w, int n)
{
    const float wx1 = st.rx, wx0 = 1.f - st.rx;
    const float wy1 = st.ry, wy0 = 1.f - st.ry;
    const float wz1 = st.rz, wz0 = 1.f - st.rz;
    const float w0 = wy0 * wz0, w1 = wy0 * wz1;
    const float w2 = wy1 * wz0, w3 = wy1 * wz1;
    const uint32_t e0 = (st.sel & 1u) ? st.p0.y : st.p0.x;
    const uint32_t f0 = (st.sel & 1u) ? st.p0.x : st.p0.y;
    const uint32_t e1 = (st.sel & 2u) ? st.p1.y : st.p1.x;
    const uint32_t f1 = (st.sel & 2u) ? st.p1.x : st.p1.y;
    const uint32_t e2 = (st.sel & 4u) ? st.p2.y : st.p2.x;
    const uint32_t f2 = (st.sel & 4u) ? st.p2.x : st.p2.y;
    const uint32_t e3 = (st.sel & 8u) ? st.p3.y : st.p3.x;
    const uint32_t f3 = (st.sel & 8u) ? st.p3.x : st.p3.y;
    float a0 = 0.f, a1 = 0.f;
    a0 = fmaf(w0, fmaf(wx0, bflo(e0), wx1 * bflo(f0)), a0);
    a1 = fmaf(w0, fmaf(wx0, bfhi(e0), wx1 * bfhi(f0)), a1);
    a0 = fmaf(w1, fmaf(wx0, bflo(e1), wx1 * bflo(f1)), a0);
    a1 = fmaf(w1, fmaf(wx0, bfhi(e1), wx1 * bfhi(f1)), a1);
    a0 = fmaf(w2, fmaf(wx0, bflo(e2), wx1 * bflo(f2)), a0);
    a1 = fmaf(w2, fmaf(wx0, bfhi(e2), wx1 * bfhi(f2)), a1);
    a0 = fmaf(w3, fmaf(wx0, bflo(e3), wx1 * bflo(f3)), a0);
    a1 = fmaf(w3, fmaf(wx0, bfhi(e3), wx1 * bfhi(f3)), a1);
    w[n] = bf16_rtne_hi(a0) | (bf16_rtne_hi(a1) << 16);
}

__global__ __launch_bounds__(256) void fine_kernel(
    const float* __restrict__ x,
    const uint32_t* __restrict__ packed,
    uint32_t* __restrict__ lvl_out)
{
    const int b = blockIdx.x;
    const int level = 7 + (b >> 11);       // level-at-a-time machine fill
    const int chunk = b & 2047;

    const float r = c_res[level];
    const uint32_t* __restrict__ tab = packed + (size_t)level * kTableSize;
    uint32_t* __restrict__ w = lvl_out + (size_t)level * kPoints;

    const int n0 = chunk * 1024 + threadIdx.x;

    PtSt A, B;
    issue_pt(A, x, n0 + 0 * 256, r, tab);
    issue_pt(B, x, n0 + 1 * 256, r, tab);
    __builtin_amdgcn_sched_barrier(0);
    consume_pt(A, w, n0 + 0 * 256);
    __builtin_amdgcn_sched_barrier(0);
    issue_pt(A, x, n0 + 2 * 256, r, tab);
    __builtin_amdgcn_sched_barrier(0);
    consume_pt(B, w, n0 + 1 * 256);
    __builtin_amdgcn_sched_barrier(0);
    issue_pt(B, x, n0 + 3 * 256, r, tab);
    __builtin_amdgcn_sched_barrier(0);
    consume_pt(A, w, n0 + 2 * 256);
    __builtin_amdgcn_sched_barrier(0);
    consume_pt(B, w, n0 + 3 * 256);
}

// ---------------- pass 2: level-major bf16 -> [N][32] f32 ----------------
__global__ __launch_bounds__(256) void untile_kernel(
    const uint32_t* __restrict__ lvl_out, float* __restrict__ out)
{
    const int n = blockIdx.x * 256 + threadIdx.x;
    float vals[2 * kLevels];
#pragma unroll
    for (int l = 0; l < kLevels; ++l) {
        const uint32_t u = lvl_out[(size_t)l * kPoints + n];
        vals[2 * l + 0] = bflo(u);
        vals[2 * l + 1] = bfhi(u);
    }
    float4* o4 = reinterpret_cast<float4*>(out + (size_t)n * (2 * kLevels));
#pragma unroll
    for (int kq = 0; kq < 8; ++kq) {
        o4[kq] = make_float4(vals[4 * kq + 0], vals[4 * kq + 1],
                             vals[4 * kq + 2], vals[4 * kq + 3]);
    }
}

// ---------------- fallbacks (round-0/round-2 proven paths) --------------
__device__ __forceinline__ void eval_level(
    float px, float py, float pz, float r,
    const uint32_t* __restrict__ tab, float& a0, float& a1)
{
    const float tx = px * r, ty = py * r, tz = pz * r;
    const float fx = floorf(tx), fy = floorf(ty), fz = floorf(tz);
    const int bx = (int)fx, by = (int)fy, bz = (int)fz;
    const float rx = tx - fx, ry = ty - fy, rz = tz - fz;

    const uint32_t hx0 = (uint32_t)bx;
    const uint32_t hx1 = (uint32_t)(bx + 1);
    const uint32_t hy0 = (uint32_t)by * 2654435761u;
    const uint32_t hy1 = (uint32_t)(by + 1) * 2654435761u;
    const uint32_t hz0 = (uint32_t)bz * 805459861u;
    const uint32_t hz1 = (uint32_t)(bz + 1) * 805459861u;

    const float wx1 = rx, wx0 = 1.0f - rx;
    const float wy1 = ry, wy0 = 1.0f - ry;
    const float wz1 = rz, wz0 = 1.0f - rz;

    a0 = 0.0f; a1 = 0.0f;
#pragma unroll
    for (int c = 0; c < 8; ++c) {
        const uint32_t h = (((c & 4) ? hx1 : hx0) ^
                            ((c & 2) ? hy1 : hy0) ^
                            ((c & 1) ? hz1 : hz0)) & kMask;
        const uint32_t e = tab[h];
        const float w = ((c & 4) ? wx1 : wx0) *
                        ((c & 2) ? wy1 : wy0) *
                        ((c & 1) ? wz1 : wz0);
        a0 = fmaf(w, bflo(e), a0);
        a1 = fmaf(w, bfhi(e), a1);
    }
}

__global__ __launch_bounds__(256) void direct_kernel(
    const float* __restrict__ x,
    const float* __restrict__ tables,
    float* __restrict__ out)
{
    const int n = blockIdx.x * 256 + threadIdx.x;
    float px = fminf(fmaxf(x[3 * n + 0], 0.0f), 1.0f);
    float py = fminf(fmaxf(x[3 * n + 1], 0.0f), 1.0f);
    float pz = fminf(fmaxf(x[3 * n + 2], 0.0f), 1.0f);

    const float res_tab[kLevels] = {
        16.f, 20.f, 25.f, 32.f, 40.f, 50.f, 64.f, 80.f,
        101.f, 128.f, 161.f, 203.f, 256.f, 322.f, 406.f, 512.f};

    float acc[2 * kLevels];
#pragma unroll
    for (int l = 0; l < kLevels; ++l) {
        const float r = res_tab[l];
        const float tx = px * r, ty = py * r, tz = pz * r;
        const float fx = floorf(tx), fy = floorf(ty), fz = floorf(tz);
        const int bx = (int)fx, by = (int)fy, bz = (int)fz;
        const float rx = tx - fx, ry = ty - fy, rz = tz - fz;
        const uint32_t hx0 = (uint32_t)bx;
        const uint32_t hx1 = (uint32_t)(bx + 1);
        const uint32_t hy0 = (uint32_t)by * 2654435761u;
        const uint32_t hy1 = (uint32_t)(by + 1) * 2654435761u;
        const uint32_t hz0 = (uint32_t)bz * 805459861u;
        const uint32_t hz1 = (uint32_t)(bz + 1) * 805459861u;
        const float wx1 = rx, wx0 = 1.0f - rx;
        const float wy1 = ry, wy0 = 1.0f - ry;
        const float wz1 = rz, wz0 = 1.0f - rz;
        const float2* __restrict__ tab =
            reinterpret_cast<const float2*>(tables) + (size_t)l * kTableSize;
        float a0 = 0.0f, a1 = 0.0f;
#pragma unroll
        for (int c = 0; c < 8; ++c) {
            const uint32_t h = (((c & 4) ? hx1 : hx0) ^
                                ((c & 2) ? hy1 : hy0) ^
                                ((c & 1) ? hz1 : hz0)) & kMask;
            const float2 e = tab[h];
            const float w = ((c & 4) ? wx1 : wx0) *
                            ((c & 2) ? wy1 : wy0) *
                            ((c & 1) ? wz1 : wz0);
            a0 = fmaf(w, e.x, a0);
            a1 = fmaf(w, e.y, a1);
        }
        acc[2 * l + 0] = a0;
        acc[2 * l + 1] = a1;
    }
    float4* o4 = reinterpret_cast<float4*>(out + (size_t)n * (2 * kLevels));
#pragma unroll
    for (int kq = 0; kq < 8; ++kq) {
        o4[kq] = make_float4(acc[4 * kq + 0], acc[4 * kq + 1],
                             acc[4 * kq + 2], acc[4 * kq + 3]);
    }
}

__global__ __launch_bounds__(256) void direct_packed_kernel(
    const float* __restrict__ x,
    const uint32_t* __restrict__ packed,
    float* __restrict__ out)
{
    const int n = blockIdx.x * 256 + threadIdx.x;
    float px = fminf(fmaxf(x[3 * n + 0], 0.0f), 1.0f);
    float py = fminf(fmaxf(x[3 * n + 1], 0.0f), 1.0f);
    float pz = fminf(fmaxf(x[3 * n + 2], 0.0f), 1.0f);

    const float res_tab[kLevels] = {
        16.f, 20.f, 25.f, 32.f, 40.f, 50.f, 64.f, 80.f,
        101.f, 128.f, 161.f, 203.f, 256.f, 322.f, 406.f, 512.f};

    float acc[2 * kLevels];
#pragma unroll
    for (int l = 0; l < kLevels; ++l) {
        float a0, a1;
        eval_level(px, py, pz, res_tab[l],
                   packed + (size_t)l * kTableSize, a0, a1);
        acc[2 * l + 0] = a0;
        acc[2 * l + 1] = a1;
    }
    float4* o4 = reinterpret_cast<float4*>(out + (size_t)n * (2 * kLevels));
#pragma unroll
    for (int kq = 0; kq < 8; ++kq) {
        o4[kq] = make_float4(acc[4 * kq + 0], acc[4 * kq + 1],
                             acc[4 * kq + 2], acc[4 * kq + 3]);
    }
}

extern "C" void kernel_launch(void* const* d_in, const int* in_sizes, int n_in,
                              void* d_out, int out_size, void* d_ws, size_t ws_size,
                              hipStream_t stream) {
    const float* x = (const float*)d_in[0];       // [2^21, 3] f32
    const float* tables = (const float*)d_in[1];  // [16, 2^19, 2] f32
    float* out = (float*)d_out;                   // [2^21, 32] f32

    if (ws_size >= kPackedBytes + kLvlOutBytes) {
        char* ws = (char*)d_ws;
        uint32_t* packed = (uint32_t*)ws;
        uint32_t* lvl_out = (uint32_t*)(ws + kPackedBytes);
        uint32_t* dense012 = (uint32_t*)ws;  // overlays packed[0] (unused)

        // pack only levels 7-15 (fine path).
        hipLaunchKernelGGL(pack_tables_kernel,
                           dim3((9 << 19) / 2 / 256), dim3(256),
                           0, stream, tables, packed, (7 << 19) / 2);
        hipLaunchKernelGGL(build_dense012_kernel,
                           dim3((kNDense + 255) / 256), dim3(256),
                           0, stream, tables, dense012);
        // two-step vox build: dense grids D3-6 (1 gather/corner), then
        // cluster assembly from D (cache-local reads).
        hipLaunchKernelGGL(build_denseD_kernel,
                           dim3((kVTot + 255) / 256), dim3(256),
                           0, stream, tables, ws);
        hipLaunchKernelGGL(build_vox_kernel,
                           dim3((kVTot + 255) / 256), dim3(256),
                           0, stream, ws);
        // pass A: levels 0-2 (LDS), 1024 blocks x 512 thr x 4 pts
        hipLaunchKernelGGL(coarse_kernel, dim3(kPoints / 2048), dim3(512),
                           0, stream, x, dense012, lvl_out);
        // pass B: levels 3-6 (voxel clusters, pipelined), 4 x 2048 blocks
        hipLaunchKernelGGL(mid_kernel, dim3(4 * 2048), dim3(256),
                           0, stream, x, (const char*)ws, lvl_out);
        // pass C: levels 7-15 (hashed, pinned 2-deep pipe), 9 x 2048 blocks
        hipLaunchKernelGGL(fine_kernel, dim3(9 * 2048), dim3(256),
                           0, stream, x, packed, lvl_out);
        // pass 2
        hipLaunchKernelGGL(untile_kernel, dim3(kPoints / 256), dim3(256),
                           0, stream, lvl_out, out);
    } else if (ws_size >= kPackedBytes) {
        uint32_t* packed = (uint32_t*)d_ws;
        hipLaunchKernelGGL(pack_tables_kernel,
                           dim3((kLevels * kTableSize / 2) / 256), dim3(256),
                           0, stream, tables, packed, 0);
        hipLaunchKernelGGL(direct_packed_kernel, dim3(kPoints / 256), dim3(256),
                           0, stream, x, packed, out);
    } else {
        hipLaunchKernelGGL(direct_kernel, dim3(kPoints / 256), dim3(256),
                           0, stream, x, tables, out);
    }
}